// Round 10
// baseline (227.662 us; speedup 1.0000x reference)
//
#include <hip/hip_runtime.h>
#include <math.h>

typedef __attribute__((ext_vector_type(4))) int i32x4;
typedef __attribute__((ext_vector_type(16))) int i32x16;

namespace {
constexpr int N_ = 3136;
constexpr int M_ = N_ * 8;       // 25088 GEMM rows (n*8+z)
// ws layout (bytes)
constexpr size_t FIN_OFF   = 0;      // float[2]: amax, wmax
constexpr size_t AMAXP_OFF = 256;    // float[896] partials
constexpr size_t WMAXP_OFF = 4096;   // float[256] partials
constexpr size_t CHS_OFF   = 6144;   // float[512]
constexpr size_t DUM_OFF   = 8192;   // int[3136*2] dummy halves (25 KB)
constexpr size_t ACT_OFF   = 36864;  // u8[25088][512]
constexpr size_t WGT_OFF   = ACT_OFF + (size_t)M_ * 512;  // u8[4096][512]
}

// offset=0 ALWAYS: the builtin's imm-offset arg is NOT applied to the global
// address for LDS-DMA on gfx950 (round-3 pass vs round-4 fail evidence).
__device__ __forceinline__ void gload(const char* g, char* l) {
  __builtin_amdgcn_global_load_lds(
      (const __attribute__((address_space(1))) char*)g,
      (__attribute__((address_space(3))) char*)l, 16, 0, 0);
}

// ---------- k1: amax partials (endpoint trick) + wmax partials + chs ----------
__global__ __launch_bounds__(256) void prep1_kernel(
    const float* __restrict__ x, const float* __restrict__ w,
    const float* __restrict__ gamma, const float* __restrict__ beta,
    const float* __restrict__ mean, const float* __restrict__ var,
    float* __restrict__ amaxp, float* __restrict__ wmaxp, float* __restrict__ chs) {
#pragma clang fp contract(off)
  __shared__ float red[4];
  const int bx = blockIdx.x, tid = threadIdx.x;
  if (bx < 896) {           // amax: thread = 28-float segment of one (b,c) row
    int id = bx * 256 + tid;
    int row = id / 28;
    int seg = id - row * 28;
    int c = row & 511;
    const float4* p = (const float4*)(x + (size_t)row * 784 + seg * 28);
    float mn = 1e30f, mx = -1e30f;
#pragma unroll
    for (int i = 0; i < 7; ++i) {
      float4 v = p[i];
      mn = fminf(mn, fminf(fminf(v.x, v.y), fminf(v.z, v.w)));
      mx = fmaxf(mx, fmaxf(fmaxf(v.x, v.y), fmaxf(v.z, v.w)));
    }
    float vf = var[c] + 1e-5f;
    float sc = (float)(1.0 / sqrt((double)vf)) * gamma[c];
    float f1 = (mn - mean[c]) * sc + beta[c];
    float f2 = (mx - mean[c]) * sc + beta[c];
    float m = fmaxf(fmaxf(f1, f2), 0.f);   // relu(affine) extrema at endpoints
#pragma unroll
    for (int o = 32; o > 0; o >>= 1) m = fmaxf(m, __shfl_down(m, o, 64));
    if ((tid & 63) == 0) red[tid >> 6] = m;
    __syncthreads();
    if (tid == 0) amaxp[bx] = fmaxf(fmaxf(red[0], red[1]), fmaxf(red[2], red[3]));
  } else if (bx < 1152) {   // wmax
    int id = (bx - 896) * 256 + tid;
    const float4* p = (const float4*)w + (size_t)id * 2;
    float4 v0 = p[0], v1 = p[1];
    float m = fmaxf(fmaxf(fmaxf(fabsf(v0.x), fabsf(v0.y)), fmaxf(fabsf(v0.z), fabsf(v0.w))),
                    fmaxf(fmaxf(fabsf(v1.x), fabsf(v1.y)), fmaxf(fabsf(v1.z), fabsf(v1.w))));
#pragma unroll
    for (int o = 32; o > 0; o >>= 1) m = fmaxf(m, __shfl_down(m, o, 64));
    if ((tid & 63) == 0) red[tid >> 6] = m;
    __syncthreads();
    if (tid == 0) wmaxp[bx - 896] = fmaxf(fmaxf(red[0], red[1]), fmaxf(red[2], red[3]));
  } else {                  // chs
    int c = (bx - 1152) * 256 + tid;
    float vf = var[c] + 1e-5f;
    chs[c] = (float)(1.0 / sqrt((double)vf)) * gamma[c];
  }
}

// ---------- k2: pack_x + per-(n,chalf) dummy partial (bx<448) | pack_w (bx>=448) ----------
__global__ __launch_bounds__(256) void pack_xw_kernel(
    const float* __restrict__ x, const float* __restrict__ mean,
    const float* __restrict__ beta, const float* __restrict__ chs,
    const float* __restrict__ amaxp, const float* __restrict__ w,
    const float* __restrict__ wmaxp, unsigned* __restrict__ act,
    unsigned* __restrict__ wgt, int* __restrict__ dummy_part,
    float* __restrict__ fin) {
#pragma clang fp contract(off)
  const int bx = blockIdx.x, tid = threadIdx.x;
  if (bx < 448) {
    __shared__ float samax;
    __shared__ unsigned char sx[14 * 256];
    const int chalf = bx & 1;
    const int bh = bx >> 1;
    const int b = bh / 14, h2 = bh - b * 14;
    if (tid < 64) {
      float m = 0.f;
      for (int i = tid; i < 896; i += 64) m = fmaxf(m, amaxp[i]);
#pragma unroll
      for (int o = 32; o > 0; o >>= 1) m = fmaxf(m, __shfl_down(m, o, 64));
      if (tid == 0) {
        float a = fmaxf(m, 1e-8f);
        samax = a;
        if (bx == 0) fin[0] = a;
      }
    }
    __syncthreads();
    const float amax = samax;
    const int cbase = chalf * 256;
    for (int it = 0; it < 7; ++it) {
      int id = it * 256 + tid;
      int cl = id / 7, q = id - cl * 7;
      int c = cbase + cl;
      const float4 v = *(const float4*)(x + (size_t)(b * 512 + c) * 784 + h2 * 56 + q * 4);
      float sc = chs[c], mu = mean[c], be = beta[c];
      float f0 = fmaxf((v.x - mu) * sc + be, 0.f);
      int i0 = (int)rintf(fminf(fmaxf(f0 / amax, 0.f), 1.f) * 255.0f);
      float f2 = fmaxf((v.z - mu) * sc + be, 0.f);
      int i2 = (int)rintf(fminf(fmaxf(f2 / amax, 0.f), 1.f) * 255.0f);
      sx[(2 * q) * 256 + cl] = (unsigned char)i0;
      sx[(2 * q + 1) * 256 + cl] = (unsigned char)i2;
    }
    __syncthreads();
    const int nbase = b * 196 + h2 * 14;
    const int lane = tid & 63;
    for (int it = 0; it < 4; ++it) {
      int id = it * 256 + tid;
      if (id < 896) {
        int cql = id & 63, w2 = id >> 6;   // whole wave shares one w2
        unsigned v = *(const unsigned*)(sx + w2 * 256 + cql * 4);
        int n = nbase + w2;
        int cq = chalf * 64 + cql;
        int dsum = 0;
#pragma unroll
        for (int z = 0; z < 8; ++z) {
          unsigned word = (v >> z) & 0x01010101u;
          act[(size_t)(n * 8 + z) * 128 + cq] = word;
          int xs = __popc(word);           // 4-channel bit count
          xs += __shfl_xor(xs, 1, 64);
          xs += __shfl_xor(xs, 2, 64);
          xs += __shfl_xor(xs, 4, 64);
          xs += __shfl_xor(xs, 8, 64);
          xs += __shfl_xor(xs, 16, 64);    // per-32-lane group: xsum(n,z,g)
          unsigned q0 = (__umul24((unsigned)xs, 51610u) + 524288u) >> 20;   // round(63x/1280)
          unsigned q3 = (__umul24((unsigned)xs, 361268u) + 524288u) >> 20;  // round(441x/1280)
          dsum += (int)((__umul24(q0, 21u) + (q3 << 6)) << z);
        }
        dsum += __shfl_xor(dsum, 32, 64);  // combine the 2 g's in this chalf
        if (lane == 0) dummy_part[n * 2 + chalf] = dsum;
      }
    }
  } else {
    __shared__ float swmax;
    const int bx2 = bx - 448;
    if (tid < 64) {
      float m = fmaxf(fmaxf(wmaxp[tid], wmaxp[tid + 64]),
                      fmaxf(wmaxp[tid + 128], wmaxp[tid + 192]));
#pragma unroll
      for (int o = 32; o > 0; o >>= 1) m = fmaxf(m, __shfl_down(m, o, 64));
      if (tid == 0) {
        float a = fmaxf(m, 1e-8f);
        swmax = a;
        if (bx2 == 0) fin[1] = a;
      }
    }
    __syncthreads();
    const float wmax = swmax;
    int t = bx2 * 256 + tid;
    int c16 = t & 31, k = (t >> 5) & 3, o = t >> 7;
    unsigned words[4];
#pragma unroll
    for (int q = 0; q < 4; ++q) {
      unsigned wd = 0;
#pragma unroll
      for (int j = 0; j < 4; ++j) {
        int c = c16 * 16 + q * 4 + j;
        float v = fminf(fmaxf(w[(size_t)o * 512 + c] / wmax, -1.f), 1.f);
        int wi = (int)rintf(v * 127.0f);
        unsigned wu = (unsigned)(wi + 128);
        unsigned cell = (wu >> (2 * k)) & 3u;
        wd |= (3u * cell + 1u) << (8 * j);
      }
      words[q] = wd;
    }
    *(uint4*)(wgt + ((size_t)(o * 4 + k) * 512 + c16 * 16) / 4) =
        make_uint4(words[0], words[1], words[2], words[3]);
  }
}

// ---------- k3: main. grid (64 cblk, 49 mslice). Persistent B in LDS (32 KB,
// loaded once, ONE barrier); 4 mblks x 4 g, zero internal barriers.
// Wave = 32 M-rows x 64 cols; A double-buffered in regs one g ahead;
// accumulator chains start from persistent zero vector (no per-unit init).

#define APREF(off_, p_) {                                   \
  av[p_][0] = *(const i32x4*)(gA + (off_) +  0);            \
  av[p_][1] = *(const i32x4*)(gA + (off_) + 32);            \
  av[p_][2] = *(const i32x4*)(gA + (off_) + 64);            \
  av[p_][3] = *(const i32x4*)(gA + (off_) + 96);            \
}

// one g: 8 MFMAs (2 independent chains seeded from zvec), quantize 32 elems
#define GCOMP(g_, p_) {                                                       \
  i32x4 b00 = *(const i32x4*)(rB + (g_) * 8192);                              \
  i32x4 b10 = *(const i32x4*)(rB + (g_) * 8192 + 512);                        \
  i32x16 c0 = __builtin_amdgcn_mfma_i32_32x32x32_i8(av[p_][0], b00, zvec, 0, 0, 0); \
  i32x16 c1 = __builtin_amdgcn_mfma_i32_32x32x32_i8(av[p_][0], b10, zvec, 0, 0, 0); \
  _Pragma("unroll")                                                           \
  for (int j = 1; j < 4; ++j) {                                               \
    i32x4 b0 = *(const i32x4*)(rB + (g_) * 8192 + j * 2048);                  \
    i32x4 b1 = *(const i32x4*)(rB + (g_) * 8192 + j * 2048 + 512);            \
    c0 = __builtin_amdgcn_mfma_i32_32x32x32_i8(av[p_][j], b0, c0, 0, 0, 0);   \
    c1 = __builtin_amdgcn_mfma_i32_32x32x32_i8(av[p_][j], b1, c1, 0, 0, 0);   \
  }                                                                           \
  _Pragma("unroll")                                                           \
  for (int e = 0; e < 16; ++e) {                                              \
    unsigned q0q = (__umul24((unsigned)c0[e], 51610u) + 524288u) >> 20;       \
    acc[0][e >> 2] += (int)(q0q << shr[e & 3]);                               \
    unsigned q1q = (__umul24((unsigned)c1[e], 51610u) + 524288u) >> 20;       \
    acc[1][e >> 2] += (int)(q1q << shr[e & 3]);                               \
  }                                                                           \
}

// unit u = i*4+g; prefetches unit u+1 (compile-time offsets), computes unit u
#define GUNIT(i_, g_, pref_) {                                                \
  const int p_ = ((i_) * 4 + (g_)) & 1;                                       \
  if (pref_) {                                                                \
    const int nu = (i_) * 4 + (g_) + 1;                                       \
    APREF((nu >> 2) * 65536 + (nu & 3) * 128, 1 - p_)                         \
  }                                                                           \
  GCOMP(g_, p_)                                                               \
}

#define MBLK_EPI(i_) {                                                        \
  int sums[2][4];                                                             \
  _Pragma("unroll")                                                           \
  for (int cs = 0; cs < 2; ++cs)                                              \
    _Pragma("unroll")                                                         \
    for (int cc = 0; cc < 4; ++cc) {                                          \
      int v = acc[cs][cc];                                                    \
      v += __shfl_xor(v, 1, 64);                                              \
      v += __shfl_xor(v, 2, 64);                                              \
      v += __shfl_xor(v, 32, 64);                                             \
      sums[cs][cc] = v;                                                       \
      acc[cs][cc] = 0;                                                        \
    }                                                                         \
  if ((lane & 3) == 0 && lane < 32) {                                         \
    const int ol = lane >> 2;                                                 \
    _Pragma("unroll")                                                         \
    for (int cc = 0; cc < 4; ++cc) {                                          \
      int n = (mslice * 4 + (i_)) * 16 + wm * 4 + cc;                         \
      int d = dp[n * 2] + dp[n * 2 + 1];                                      \
      int b = n / 196, hw = n - b * 196;                                      \
      _Pragma("unroll")                                                       \
      for (int cs = 0; cs < 2; ++cs) {                                        \
        int o = cblk * 16 + cs * 8 + ol;                                      \
        size_t idx = ((size_t)(b * 1024 + o)) * 196 + hw;                     \
        out[idx] = (float)(sums[cs][cc] - d) * scale + y[idx];                \
      }                                                                       \
    }                                                                         \
  }                                                                           \
}

#define MBLK(i_, last_) {                                                     \
  GUNIT(i_, 0, 1) GUNIT(i_, 1, 1) GUNIT(i_, 2, 1) GUNIT(i_, 3, !(last_))     \
  MBLK_EPI(i_)                                                                \
}

__global__ __launch_bounds__(256, 4) void shortcutq_main_kernel(
    const char* __restrict__ act, const char* __restrict__ wgt,
    const int* __restrict__ dp, const float* __restrict__ y,
    const float* __restrict__ fin, float* __restrict__ out) {
  __shared__ __align__(16) char lds[32768];   // B slice: [kidx(32)][row(64)][16B]
  const int tid = threadIdx.x;
  const int cblk = blockIdx.x;    // 64: 16 o x 4 k cols
  const int mslice = blockIdx.y;  // 49: 4 mblks each
  const int lane = tid & 63, wm = tid >> 6;

  const char* gA = act + (size_t)(mslice * 4 * 128 + wm * 32 + (lane & 31)) * 512 +
                   (lane >> 5) * 16;
  const char* gB = wgt + (size_t)(cblk * 64 + (tid & 63)) * 512 + (tid >> 6) * 16;
  const char* rB = lds + (lane >> 5) * 1024 + (lane & 31) * 16;

  const int shb = 4 * (lane >> 5) + 2 * (lane & 3);
  int shr[4] = {shb, shb + 1, shb + 2, shb + 3};

  i32x4 av[2][4];
  int acc[2][4];
#pragma unroll
  for (int cs = 0; cs < 2; ++cs)
#pragma unroll
    for (int cc = 0; cc < 4; ++cc) acc[cs][cc] = 0;
  i32x16 zvec;
#pragma unroll
  for (int e = 0; e < 16; ++e) zvec[e] = 0;

  APREF(0, 0)                      // unit 0 A-frags, in flight with B DMA
#pragma unroll
  for (int l = 0; l < 8; ++l)
    gload(gB + l * 64, lds + l * 4096 + tid * 16);
  __syncthreads();                 // the ONLY barrier

  const float scale = (float)((128.0 * (3.0 + 1.0 / 3.0)) / 63.0) *
                      (fin[1] / 127.0f) * (fin[0] / 255.0f);

  MBLK(0, 0) MBLK(1, 0) MBLK(2, 0) MBLK(3, 1)
}

extern "C" void kernel_launch(void* const* d_in, const int* in_sizes, int n_in,
                              void* d_out, int out_size, void* d_ws, size_t ws_size,
                              hipStream_t stream) {
  const float* x     = (const float*)d_in[0];
  const float* y     = (const float*)d_in[1];
  const float* gamma = (const float*)d_in[2];
  const float* beta  = (const float*)d_in[3];
  const float* mean  = (const float*)d_in[4];
  const float* var   = (const float*)d_in[5];
  const float* w     = (const float*)d_in[6];
  float* out = (float*)d_out;

  char* wsb = (char*)d_ws;
  float* fin    = (float*)(wsb + FIN_OFF);
  float* amaxp  = (float*)(wsb + AMAXP_OFF);
  float* wmaxp  = (float*)(wsb + WMAXP_OFF);
  float* chs    = (float*)(wsb + CHS_OFF);
  int*   dum    = (int*)(wsb + DUM_OFF);
  char*  actb   = wsb + ACT_OFF;
  char*  wgtb   = wsb + WGT_OFF;

  hipLaunchKernelGGL(prep1_kernel, dim3(1154), dim3(256), 0, stream,
                     x, w, gamma, beta, mean, var, amaxp, wmaxp, chs);
  hipLaunchKernelGGL(pack_xw_kernel, dim3(960), dim3(256), 0, stream,
                     x, mean, beta, chs, amaxp, w, wmaxp,
                     (unsigned*)actb, (unsigned*)wgtb, dum, fin);
  hipLaunchKernelGGL(shortcutq_main_kernel, dim3(64, 49), dim3(256), 0, stream,
                     actb, wgtb, dum, y, fin, out);
}

// Round 11
// 180.236 us; speedup vs baseline: 1.2631x; 1.2631x over previous
//
#include <hip/hip_runtime.h>
#include <math.h>

typedef __attribute__((ext_vector_type(4))) int i32x4;
typedef __attribute__((ext_vector_type(16))) int i32x16;

namespace {
constexpr int N_ = 3136;
constexpr int M_ = N_ * 8;       // 25088 GEMM rows (n*8+z)
// ws layout (bytes)
constexpr size_t FIN_OFF   = 0;      // float[2]: amax, wmax
constexpr size_t AMAXP_OFF = 256;    // float[896] partials
constexpr size_t WMAXP_OFF = 4096;   // float[256] partials
constexpr size_t CHS_OFF   = 6144;   // float[512]
constexpr size_t DUM_OFF   = 8192;   // int[3136]
constexpr size_t ACT_OFF   = 32768;  // act2: 784 tiles x 16 KB (tiled layout)
constexpr size_t WGT_OFF   = ACT_OFF + (size_t)M_ * 512;  // wgt2: 64 x 32 KB LDS images
}

// offset=0 ALWAYS: the builtin's imm-offset arg is NOT applied to the global
// address for LDS-DMA on gfx950 (round-3 pass vs round-4 fail evidence).
__device__ __forceinline__ void gload(const char* g, char* l) {
  __builtin_amdgcn_global_load_lds(
      (const __attribute__((address_space(1))) char*)g,
      (__attribute__((address_space(3))) char*)l, 16, 0, 0);
}

// ---------- k1: amax partials (endpoint trick) + wmax partials + chs ----------
__global__ __launch_bounds__(256) void prep1_kernel(
    const float* __restrict__ x, const float* __restrict__ w,
    const float* __restrict__ gamma, const float* __restrict__ beta,
    const float* __restrict__ mean, const float* __restrict__ var,
    float* __restrict__ amaxp, float* __restrict__ wmaxp, float* __restrict__ chs) {
#pragma clang fp contract(off)
  __shared__ float red[4];
  const int bx = blockIdx.x, tid = threadIdx.x;
  if (bx < 896) {           // amax: thread = 28-float segment of one (b,c) row
    int id = bx * 256 + tid;
    int row = id / 28;
    int seg = id - row * 28;
    int c = row & 511;
    const float4* p = (const float4*)(x + (size_t)row * 784 + seg * 28);
    float mn = 1e30f, mx = -1e30f;
#pragma unroll
    for (int i = 0; i < 7; ++i) {
      float4 v = p[i];
      mn = fminf(mn, fminf(fminf(v.x, v.y), fminf(v.z, v.w)));
      mx = fmaxf(mx, fmaxf(fmaxf(v.x, v.y), fmaxf(v.z, v.w)));
    }
    float vf = var[c] + 1e-5f;
    float sc = (float)(1.0 / sqrt((double)vf)) * gamma[c];
    float f1 = (mn - mean[c]) * sc + beta[c];
    float f2 = (mx - mean[c]) * sc + beta[c];
    float m = fmaxf(fmaxf(f1, f2), 0.f);   // relu(affine) extrema at endpoints
#pragma unroll
    for (int o = 32; o > 0; o >>= 1) m = fmaxf(m, __shfl_down(m, o, 64));
    if ((tid & 63) == 0) red[tid >> 6] = m;
    __syncthreads();
    if (tid == 0) amaxp[bx] = fmaxf(fmaxf(red[0], red[1]), fmaxf(red[2], red[3]));
  } else if (bx < 1152) {   // wmax
    int id = (bx - 896) * 256 + tid;
    const float4* p = (const float4*)w + (size_t)id * 2;
    float4 v0 = p[0], v1 = p[1];
    float m = fmaxf(fmaxf(fmaxf(fabsf(v0.x), fabsf(v0.y)), fmaxf(fabsf(v0.z), fabsf(v0.w))),
                    fmaxf(fmaxf(fabsf(v1.x), fabsf(v1.y)), fmaxf(fabsf(v1.z), fabsf(v1.w))));
#pragma unroll
    for (int o = 32; o > 0; o >>= 1) m = fmaxf(m, __shfl_down(m, o, 64));
    if ((tid & 63) == 0) red[tid >> 6] = m;
    __syncthreads();
    if (tid == 0) wmaxp[bx - 896] = fmaxf(fmaxf(red[0], red[1]), fmaxf(red[2], red[3]));
  } else {                  // chs
    int c = (bx - 1152) * 256 + tid;
    float vf = var[c] + 1e-5f;
    chs[c] = (float)(1.0 / sqrt((double)vf)) * gamma[c];
  }
}

// ---------- k2: pack_x (bx<448, tiled act2 layout) | pack_w (bx>=448, LDS-image wgt2) ----------
__global__ __launch_bounds__(256) void pack_xw_kernel(
    const float* __restrict__ x, const float* __restrict__ mean,
    const float* __restrict__ beta, const float* __restrict__ chs,
    const float* __restrict__ amaxp, const float* __restrict__ w,
    const float* __restrict__ wmaxp, unsigned* __restrict__ act,
    unsigned* __restrict__ wgt, float* __restrict__ fin) {
#pragma clang fp contract(off)
  const int bx = blockIdx.x, tid = threadIdx.x;
  if (bx < 448) {
    __shared__ float samax;
    __shared__ unsigned char sx[14 * 256];
    const int chalf = bx & 1;
    const int bh = bx >> 1;
    const int b = bh / 14, h2 = bh - b * 14;
    if (tid < 64) {
      float m = 0.f;
      for (int i = tid; i < 896; i += 64) m = fmaxf(m, amaxp[i]);
#pragma unroll
      for (int o = 32; o > 0; o >>= 1) m = fmaxf(m, __shfl_down(m, o, 64));
      if (tid == 0) {
        float a = fmaxf(m, 1e-8f);
        samax = a;
        if (bx == 0) fin[0] = a;
      }
    }
    __syncthreads();
    const float amax = samax;
    const int cbase = chalf * 256;
    for (int it = 0; it < 7; ++it) {
      int id = it * 256 + tid;
      int cl = id / 7, q = id - cl * 7;
      int c = cbase + cl;
      const float4 v = *(const float4*)(x + (size_t)(b * 512 + c) * 784 + h2 * 56 + q * 4);
      float sc = chs[c], mu = mean[c], be = beta[c];
      float f0 = fmaxf((v.x - mu) * sc + be, 0.f);
      int i0 = (int)rintf(fminf(fmaxf(f0 / amax, 0.f), 1.f) * 255.0f);
      float f2 = fmaxf((v.z - mu) * sc + be, 0.f);
      int i2 = (int)rintf(fminf(fmaxf(f2 / amax, 0.f), 1.f) * 255.0f);
      sx[(2 * q) * 256 + cl] = (unsigned char)i0;
      sx[(2 * q + 1) * 256 + cl] = (unsigned char)i2;
    }
    __syncthreads();
    const int nbase = b * 196 + h2 * 14;
    for (int it = 0; it < 4; ++it) {
      int id = it * 256 + tid;
      if (id < 896) {
        int cql = id & 63, w2 = id >> 6;
        unsigned v = *(const unsigned*)(sx + w2 * 256 + cql * 4);
        int n = nbase + w2;
        int cq = chalf * 64 + cql;
        // tiled act2 address: row = n*8+z; tile = row>>5 (= n>>2, const over z)
        int g = cq >> 5, j = (cq & 31) >> 3, kh = (cq >> 2) & 1, bp = cq & 3;
        size_t base = (size_t)(n >> 2) * 16384 +
                      (size_t)(g * 4 + j) * 1024 + kh * 512 + bp * 4;
        int rowin0 = (n * 8) & 31;
#pragma unroll
        for (int z = 0; z < 8; ++z)
          act[(base + (rowin0 + z) * 16) >> 2] = (v >> z) & 0x01010101u;
      }
    }
  } else {
    __shared__ float swmax;
    const int bx2 = bx - 448;
    if (tid < 64) {
      float m = fmaxf(fmaxf(wmaxp[tid], wmaxp[tid + 64]),
                      fmaxf(wmaxp[tid + 128], wmaxp[tid + 192]));
#pragma unroll
      for (int o = 32; o > 0; o >>= 1) m = fmaxf(m, __shfl_down(m, o, 64));
      if (tid == 0) {
        float a = fmaxf(m, 1e-8f);
        swmax = a;
        if (bx2 == 0) fin[1] = a;
      }
    }
    __syncthreads();
    const float wmax = swmax;
    int t = bx2 * 256 + tid;
    int c16 = t & 31, k = (t >> 5) & 3, o = t >> 7;
    unsigned words[4];
#pragma unroll
    for (int q = 0; q < 4; ++q) {
      unsigned wd = 0;
#pragma unroll
      for (int j = 0; j < 4; ++j) {
        int c = c16 * 16 + q * 4 + j;
        float v = fminf(fmaxf(w[(size_t)o * 512 + c] / wmax, -1.f), 1.f);
        int wi = (int)rintf(v * 127.0f);
        unsigned wu = (unsigned)(wi + 128);
        unsigned cell = (wu >> (2 * k)) & 3u;
        wd |= (3u * cell + 1u) << (8 * j);
      }
      words[q] = wd;
    }
    // wgt2 = per-cblk LDS image: off = cblk*32768 + l*4096 + tid'*16,
    // where r = o*4+k, cblk=r>>6, l=c16>>2, tid' = (c16&3)*64 + (r&63)
    int r = o * 4 + k;
    size_t off = (size_t)(r >> 6) * 32768 + (size_t)(c16 >> 2) * 4096 +
                 (size_t)(((c16 & 3) << 6) + (r & 63)) * 16;
    *(uint4*)(wgt + (off >> 2)) = make_uint4(words[0], words[1], words[2], words[3]);
  }
}

// ---------- k2b: dummy from act2, fully coalesced ----------
__global__ __launch_bounds__(256) void dummy_kernel(const char* __restrict__ act2,
                                                    int* __restrict__ dummy) {
  int id = blockIdx.x * 256 + threadIdx.x;   // 784 tiles x 64 lanes
  int t = id >> 6, lane = id & 63;
  const char* p = act2 + (size_t)t * 16384 + lane * 16;  // lane = khalf*32+rowin
  int z = (t * 32 + (lane & 31)) & 7;
  int dterm = 0;
#pragma unroll
  for (int g = 0; g < 4; ++g) {
    int sg = 0;
#pragma unroll
    for (int j = 0; j < 4; ++j) {
      const uint4 v = *(const uint4*)(p + (g * 4 + j) * 1024);
      sg += __popc(v.x) + __popc(v.y) + __popc(v.z) + __popc(v.w);
    }
    int xs = sg + __shfl_xor(sg, 32, 64);   // combine k-halves
    unsigned q0 = (__umul24((unsigned)xs, 51610u) + 524288u) >> 20;   // round(63x/1280)
    unsigned q3 = (__umul24((unsigned)xs, 361268u) + 524288u) >> 20;  // round(441x/1280)
    dterm += (int)((__umul24(q0, 21u) + (q3 << 6)) << z);
  }
  dterm += __shfl_xor(dterm, 1, 64);
  dterm += __shfl_xor(dterm, 2, 64);
  dterm += __shfl_xor(dterm, 4, 64);        // sum over z within each n
  if ((lane & 39) == 0)                     // khalf==0 && rowin%8==0
    dummy[t * 4 + ((lane >> 3) & 3)] = dterm;
}

// ---------- k3: main. grid (64 cblk, 49 mslice). Persistent B in LDS (32 KB,
// loaded once via coalesced DMA, ONE barrier); 16 units, zero internal barriers.
// A register double-buffer, each load 64x16B CONTIGUOUS (tiled act2 layout).

#define APREF(off_, p_) {                                   \
  av[p_][0] = *(const i32x4*)(gA + (off_));                 \
  av[p_][1] = *(const i32x4*)(gA + (off_) + 1024);          \
  av[p_][2] = *(const i32x4*)(gA + (off_) + 2048);          \
  av[p_][3] = *(const i32x4*)(gA + (off_) + 3072);          \
}

// one g: 8 MFMAs (2 independent chains seeded from zvec), quantize 32 elems
#define GCOMP(g_, p_) {                                                       \
  i32x4 b00 = *(const i32x4*)(rB + (g_) * 8192);                              \
  i32x4 b10 = *(const i32x4*)(rB + (g_) * 8192 + 512);                        \
  i32x16 c0 = __builtin_amdgcn_mfma_i32_32x32x32_i8(av[p_][0], b00, zvec, 0, 0, 0); \
  i32x16 c1 = __builtin_amdgcn_mfma_i32_32x32x32_i8(av[p_][0], b10, zvec, 0, 0, 0); \
  _Pragma("unroll")                                                           \
  for (int j = 1; j < 4; ++j) {                                               \
    i32x4 b0 = *(const i32x4*)(rB + (g_) * 8192 + j * 2048);                  \
    i32x4 b1 = *(const i32x4*)(rB + (g_) * 8192 + j * 2048 + 512);            \
    c0 = __builtin_amdgcn_mfma_i32_32x32x32_i8(av[p_][j], b0, c0, 0, 0, 0);   \
    c1 = __builtin_amdgcn_mfma_i32_32x32x32_i8(av[p_][j], b1, c1, 0, 0, 0);   \
  }                                                                           \
  _Pragma("unroll")                                                           \
  for (int e = 0; e < 16; ++e) {                                              \
    unsigned q0q = (__umul24((unsigned)c0[e], 51610u) + 524288u) >> 20;       \
    acc[0][e >> 2] += (int)(q0q << shr[e & 3]);                               \
    unsigned q1q = (__umul24((unsigned)c1[e], 51610u) + 524288u) >> 20;       \
    acc[1][e >> 2] += (int)(q1q << shr[e & 3]);                               \
  }                                                                           \
}

// unit u = i*4+g; prefetches unit u+1 (compile-time offsets), computes unit u
#define GUNIT(i_, g_, pref_) {                                                \
  const int p_ = ((i_) * 4 + (g_)) & 1;                                       \
  if (pref_) {                                                                \
    const int nu = (i_) * 4 + (g_) + 1;                                       \
    APREF((nu >> 2) * 65536 + (nu & 3) * 4096, 1 - p_)                        \
  }                                                                           \
  GCOMP(g_, p_)                                                               \
}

#define MBLK_EPI(i_) {                                                        \
  int sums[2][4];                                                             \
  _Pragma("unroll")                                                           \
  for (int cs = 0; cs < 2; ++cs)                                              \
    _Pragma("unroll")                                                         \
    for (int cc = 0; cc < 4; ++cc) {                                          \
      int v = acc[cs][cc];                                                    \
      v += __shfl_xor(v, 1, 64);                                              \
      v += __shfl_xor(v, 2, 64);                                              \
      v += __shfl_xor(v, 32, 64);                                             \
      sums[cs][cc] = v;                                                       \
      acc[cs][cc] = 0;                                                        \
    }                                                                         \
  if ((lane & 3) == 0 && lane < 32) {                                         \
    const int ol = lane >> 2;                                                 \
    _Pragma("unroll")                                                         \
    for (int cc = 0; cc < 4; ++cc) {                                          \
      int n = (mslice * 4 + (i_)) * 16 + wm * 4 + cc;                         \
      int d = dp[n];                                                          \
      int b = n / 196, hw = n - b * 196;                                      \
      _Pragma("unroll")                                                       \
      for (int cs = 0; cs < 2; ++cs) {                                        \
        int o = cblk * 16 + cs * 8 + ol;                                      \
        size_t idx = ((size_t)(b * 1024 + o)) * 196 + hw;                     \
        out[idx] = (float)(sums[cs][cc] - d) * scale + y[idx];                \
      }                                                                       \
    }                                                                         \
  }                                                                           \
}

#define MBLK(i_, last_) {                                                     \
  GUNIT(i_, 0, 1) GUNIT(i_, 1, 1) GUNIT(i_, 2, 1) GUNIT(i_, 3, !(last_))     \
  MBLK_EPI(i_)                                                                \
}

__global__ __launch_bounds__(256, 4) void shortcutq_main_kernel(
    const char* __restrict__ act, const char* __restrict__ wgt,
    const int* __restrict__ dp, const float* __restrict__ y,
    const float* __restrict__ fin, float* __restrict__ out) {
  __shared__ __align__(16) char lds[32768];
  const int tid = threadIdx.x;
  const int cblk = blockIdx.x;    // 64: 16 o x 4 k cols
  const int mslice = blockIdx.y;  // 49: 4 mblks (16 tiles) each
  const int lane = tid & 63, wm = tid >> 6;

  // A: tile (mslice*16 + i*4 + wm); per-load 64 lanes x 16B contiguous
  const char* gA = act + (size_t)(mslice * 16 + wm) * 16384 + lane * 16;
  // B: coalesced DMA of the pre-swizzled 32 KB LDS image
  const char* gB = wgt + (size_t)cblk * 32768 + tid * 16;
  const char* rB = lds + (lane >> 5) * 1024 + (lane & 31) * 16;

  const int shb = 4 * (lane >> 5) + 2 * (lane & 3);
  int shr[4] = {shb, shb + 1, shb + 2, shb + 3};

  i32x4 av[2][4];
  int acc[2][4];
#pragma unroll
  for (int cs = 0; cs < 2; ++cs)
#pragma unroll
    for (int cc = 0; cc < 4; ++cc) acc[cs][cc] = 0;
  i32x16 zvec;
#pragma unroll
  for (int e = 0; e < 16; ++e) zvec[e] = 0;

  APREF(0, 0)                      // unit 0 A-frags, in flight with B DMA
#pragma unroll
  for (int l = 0; l < 8; ++l)
    gload(gB + l * 4096, lds + l * 4096 + tid * 16);
  __syncthreads();                 // the ONLY barrier

  const float scale = (float)((128.0 * (3.0 + 1.0 / 3.0)) / 63.0) *
                      (fin[1] / 127.0f) * (fin[0] / 255.0f);

  MBLK(0, 0) MBLK(1, 0) MBLK(2, 0) MBLK(3, 1)
}

extern "C" void kernel_launch(void* const* d_in, const int* in_sizes, int n_in,
                              void* d_out, int out_size, void* d_ws, size_t ws_size,
                              hipStream_t stream) {
  const float* x     = (const float*)d_in[0];
  const float* y     = (const float*)d_in[1];
  const float* gamma = (const float*)d_in[2];
  const float* beta  = (const float*)d_in[3];
  const float* mean  = (const float*)d_in[4];
  const float* var   = (const float*)d_in[5];
  const float* w     = (const float*)d_in[6];
  float* out = (float*)d_out;

  char* wsb = (char*)d_ws;
  float* fin    = (float*)(wsb + FIN_OFF);
  float* amaxp  = (float*)(wsb + AMAXP_OFF);
  float* wmaxp  = (float*)(wsb + WMAXP_OFF);
  float* chs    = (float*)(wsb + CHS_OFF);
  int*   dum    = (int*)(wsb + DUM_OFF);
  char*  actb   = wsb + ACT_OFF;
  char*  wgtb   = wsb + WGT_OFF;

  hipLaunchKernelGGL(prep1_kernel, dim3(1154), dim3(256), 0, stream,
                     x, w, gamma, beta, mean, var, amaxp, wmaxp, chs);
  hipLaunchKernelGGL(pack_xw_kernel, dim3(960), dim3(256), 0, stream,
                     x, mean, beta, chs, amaxp, w, wmaxp,
                     (unsigned*)actb, (unsigned*)wgtb, fin);
  hipLaunchKernelGGL(dummy_kernel, dim3(196), dim3(256), 0, stream, actb, dum);
  hipLaunchKernelGGL(shortcutq_main_kernel, dim3(64, 49), dim3(256), 0, stream,
                     actb, wgtb, dum, y, fin, out);
}

// Round 12
// 179.345 us; speedup vs baseline: 1.2694x; 1.0050x over previous
//
#include <hip/hip_runtime.h>
#include <math.h>

typedef __attribute__((ext_vector_type(4))) int i32x4;
typedef __attribute__((ext_vector_type(16))) int i32x16;

namespace {
constexpr int N_ = 3136;
constexpr int M_ = N_ * 8;       // 25088 GEMM rows (n*8+z)
// ws layout (bytes)
constexpr size_t FIN_OFF   = 0;      // float[2]: amax, wmax
constexpr size_t AMAXP_OFF = 256;    // float[896] partials
constexpr size_t WMAXP_OFF = 4096;   // float[256] partials
constexpr size_t CHS_OFF   = 6144;   // float[512]
constexpr size_t DUM_OFF   = 8192;   // int[3136*2] dummy halves
constexpr size_t ACT_OFF   = 36864;  // act2: 784 tiles x 16 KB (tiled layout)
constexpr size_t WGT_OFF   = ACT_OFF + (size_t)M_ * 512;  // wgt2: 64 x 32 KB LDS images
}

// offset=0 ALWAYS: the builtin's imm-offset arg is NOT applied to the global
// address for LDS-DMA on gfx950 (round-3 pass vs round-4 fail evidence).
__device__ __forceinline__ void gload(const char* g, char* l) {
  __builtin_amdgcn_global_load_lds(
      (const __attribute__((address_space(1))) char*)g,
      (__attribute__((address_space(3))) char*)l, 16, 0, 0);
}

// ---------- k1: amax partials (endpoint trick) + wmax partials + chs ----------
__global__ __launch_bounds__(256) void prep1_kernel(
    const float* __restrict__ x, const float* __restrict__ w,
    const float* __restrict__ gamma, const float* __restrict__ beta,
    const float* __restrict__ mean, const float* __restrict__ var,
    float* __restrict__ amaxp, float* __restrict__ wmaxp, float* __restrict__ chs) {
#pragma clang fp contract(off)
  __shared__ float red[4];
  const int bx = blockIdx.x, tid = threadIdx.x;
  if (bx < 896) {           // amax: thread = 28-float segment of one (b,c) row
    int id = bx * 256 + tid;
    int row = id / 28;
    int seg = id - row * 28;
    int c = row & 511;
    const float4* p = (const float4*)(x + (size_t)row * 784 + seg * 28);
    float mn = 1e30f, mx = -1e30f;
#pragma unroll
    for (int i = 0; i < 7; ++i) {
      float4 v = p[i];
      mn = fminf(mn, fminf(fminf(v.x, v.y), fminf(v.z, v.w)));
      mx = fmaxf(mx, fmaxf(fmaxf(v.x, v.y), fmaxf(v.z, v.w)));
    }
    float vf = var[c] + 1e-5f;
    float sc = (float)(1.0 / sqrt((double)vf)) * gamma[c];
    float f1 = (mn - mean[c]) * sc + beta[c];
    float f2 = (mx - mean[c]) * sc + beta[c];
    float m = fmaxf(fmaxf(f1, f2), 0.f);   // relu(affine) extrema at endpoints
#pragma unroll
    for (int o = 32; o > 0; o >>= 1) m = fmaxf(m, __shfl_down(m, o, 64));
    if ((tid & 63) == 0) red[tid >> 6] = m;
    __syncthreads();
    if (tid == 0) amaxp[bx] = fmaxf(fmaxf(red[0], red[1]), fmaxf(red[2], red[3]));
  } else if (bx < 1152) {   // wmax
    int id = (bx - 896) * 256 + tid;
    const float4* p = (const float4*)w + (size_t)id * 2;
    float4 v0 = p[0], v1 = p[1];
    float m = fmaxf(fmaxf(fmaxf(fabsf(v0.x), fabsf(v0.y)), fmaxf(fabsf(v0.z), fabsf(v0.w))),
                    fmaxf(fmaxf(fabsf(v1.x), fabsf(v1.y)), fmaxf(fabsf(v1.z), fabsf(v1.w))));
#pragma unroll
    for (int o = 32; o > 0; o >>= 1) m = fmaxf(m, __shfl_down(m, o, 64));
    if ((tid & 63) == 0) red[tid >> 6] = m;
    __syncthreads();
    if (tid == 0) wmaxp[bx - 896] = fmaxf(fmaxf(red[0], red[1]), fmaxf(red[2], red[3]));
  } else {                  // chs
    int c = (bx - 1152) * 256 + tid;
    float vf = var[c] + 1e-5f;
    chs[c] = (float)(1.0 / sqrt((double)vf)) * gamma[c];
  }
}

// ---------- k2: pack_x+dummy (bx<224) | pack_w (bx>=224) ----------
// pack_x block = (b, h2pair p, chalf): covers n in [b*196+28p, +28) = 7 act2
// tiles for 256 channels. Coalesced 16B act2 stores (1 KB/wave).
__global__ __launch_bounds__(256) void pack_xw_kernel(
    const float* __restrict__ x, const float* __restrict__ mean,
    const float* __restrict__ beta, const float* __restrict__ chs,
    const float* __restrict__ amaxp, const float* __restrict__ w,
    const float* __restrict__ wmaxp, unsigned* __restrict__ act,
    unsigned* __restrict__ wgt, int* __restrict__ dummy_part,
    float* __restrict__ fin) {
#pragma clang fp contract(off)
  const int bx = blockIdx.x, tid = threadIdx.x;
  if (bx < 224) {
    __shared__ float samax;
    __shared__ __align__(16) unsigned char sx[28 * 256];  // [nl][cl]
    __shared__ int dd[448];                               // [nl][gl][z]
    const int chalf = bx & 1;
    const int bp = (bx >> 1) % 7;          // h2 pair index p
    const int b = (bx >> 1) / 7;
    if (tid < 64) {
      float m = 0.f;
      for (int i = tid; i < 896; i += 64) m = fmaxf(m, amaxp[i]);
#pragma unroll
      for (int o = 32; o > 0; o >>= 1) m = fmaxf(m, __shfl_down(m, o, 64));
      if (tid == 0) {
        float a = fmaxf(m, 1e-8f);
        samax = a;
        if (bx == 0) fin[0] = a;
      }
    }
    __syncthreads();
    const float amax = samax;
    // phase 1: 3584 float4 units = (cl 0..255) x (rowsel 0..1) x (f4i 0..6)
    for (int it = 0; it < 14; ++it) {
      int id = it * 256 + tid;
      int cl = id / 14, r = id - cl * 14;
      int rowsel = r / 7, f4i = r - rowsel * 7;
      int c = chalf * 256 + cl;
      const float4 v = *(const float4*)(
          x + (size_t)(b * 512 + c) * 784 + (bp * 4 + 2 * rowsel) * 28 + f4i * 4);
      float sc = chs[c], mu = mean[c], be = beta[c];
      float f0 = fmaxf((v.x - mu) * sc + be, 0.f);
      int i0 = (int)rintf(fminf(fmaxf(f0 / amax, 0.f), 1.f) * 255.0f);
      float f2 = fmaxf((v.z - mu) * sc + be, 0.f);
      int i2 = (int)rintf(fminf(fmaxf(f2 / amax, 0.f), 1.f) * 255.0f);
      int nl = rowsel * 14 + f4i * 2;
      sx[nl * 256 + cl] = (unsigned char)i0;
      sx[(nl + 1) * 256 + cl] = (unsigned char)i2;
    }
    __syncthreads();
    // phase 2: 3584 16B units = (tilel 0..6) x (gjl 0..7) x (kh 0..1) x (row 0..31)
    const int tile0 = (b * 196 + 28 * bp) >> 2;   // 7 consecutive tiles
    for (int it = 0; it < 14; ++it) {
      int id = it * 256 + tid;
      int row = id & 31, kh = (id >> 5) & 1, gjl = (id >> 6) & 7, tilel = id >> 9;
      int nl = tilel * 4 + (row >> 3), z = row & 7;
      int cl0 = (gjl >> 2) * 128 + (gjl & 3) * 32 + kh * 16;
      const uint4 v = *(const uint4*)(sx + nl * 256 + cl0);
      uint4 o;
      o.x = (v.x >> z) & 0x01010101u;
      o.y = (v.y >> z) & 0x01010101u;
      o.z = (v.z >> z) & 0x01010101u;
      o.w = (v.w >> z) & 0x01010101u;
      size_t off = (size_t)(tile0 + tilel) * 16384 +
                   (size_t)(chalf * 8 + gjl) * 1024 + kh * 512 + row * 16;
      *(uint4*)((char*)act + off) = o;
    }
    // phase 2b: dummy partials. 448 units = (nl 0..27) x (gl 0..1) x (z 0..7)
    for (int it = 0; it < 2; ++it) {
      int id = it * 256 + tid;
      if (id < 448) {
        int z = id & 7, gl = (id >> 3) & 1, nl = id >> 4;
        const unsigned* sw = (const unsigned*)(sx + nl * 256 + gl * 128);
        int xs = 0;
#pragma unroll
        for (int wq = 0; wq < 8; ++wq) {
          uint4 vv = *(const uint4*)(sw + wq * 4);
          xs += __popc((vv.x >> z) & 0x01010101u) + __popc((vv.y >> z) & 0x01010101u) +
                __popc((vv.z >> z) & 0x01010101u) + __popc((vv.w >> z) & 0x01010101u);
        }
        unsigned q0 = (__umul24((unsigned)xs, 51610u) + 524288u) >> 20;   // round(63x/1280)
        unsigned q3 = (__umul24((unsigned)xs, 361268u) + 524288u) >> 20;  // round(441x/1280)
        dd[id] = (int)((__umul24(q0, 21u) + (q3 << 6)) << z);
      }
    }
    __syncthreads();
    if (tid < 28) {
      int s = 0;
#pragma unroll
      for (int i = 0; i < 16; ++i) s += dd[tid * 16 + i];
      dummy_part[(b * 196 + 28 * bp + tid) * 2 + chalf] = s;
    }
  } else {
    __shared__ float swmax;
    const int bx2 = bx - 224;
    if (tid < 64) {
      float m = fmaxf(fmaxf(wmaxp[tid], wmaxp[tid + 64]),
                      fmaxf(wmaxp[tid + 128], wmaxp[tid + 192]));
#pragma unroll
      for (int o = 32; o > 0; o >>= 1) m = fmaxf(m, __shfl_down(m, o, 64));
      if (tid == 0) {
        float a = fmaxf(m, 1e-8f);
        swmax = a;
        if (bx2 == 0) fin[1] = a;
      }
    }
    __syncthreads();
    const float wmax = swmax;
    int t = bx2 * 256 + tid;
    int c16 = t & 31, k = (t >> 5) & 3, o = t >> 7;
    unsigned words[4];
#pragma unroll
    for (int q = 0; q < 4; ++q) {
      unsigned wd = 0;
#pragma unroll
      for (int j = 0; j < 4; ++j) {
        int c = c16 * 16 + q * 4 + j;
        float v = fminf(fmaxf(w[(size_t)o * 512 + c] / wmax, -1.f), 1.f);
        int wi = (int)rintf(v * 127.0f);
        unsigned wu = (unsigned)(wi + 128);
        unsigned cell = (wu >> (2 * k)) & 3u;
        wd |= (3u * cell + 1u) << (8 * j);
      }
      words[q] = wd;
    }
    // wgt2 = per-cblk LDS image: r = o*4+k; off = (r>>6)*32768 + (c16>>2)*4096
    //        + ((c16&3)*64 + (r&63))*16
    int r = o * 4 + k;
    size_t off = (size_t)(r >> 6) * 32768 + (size_t)(c16 >> 2) * 4096 +
                 (size_t)(((c16 & 3) << 6) + (r & 63)) * 16;
    *(uint4*)(wgt + (off >> 2)) = make_uint4(words[0], words[1], words[2], words[3]);
  }
}

// ---------- k3: main. grid (64 cblk, 49 mslice). Persistent B in LDS (32 KB,
// loaded once via coalesced DMA, ONE barrier); 16 units, zero internal barriers.
// A register double-buffer, each load 64x16B CONTIGUOUS (tiled act2 layout).

#define APREF(off_, p_) {                                   \
  av[p_][0] = *(const i32x4*)(gA + (off_));                 \
  av[p_][1] = *(const i32x4*)(gA + (off_) + 1024);          \
  av[p_][2] = *(const i32x4*)(gA + (off_) + 2048);          \
  av[p_][3] = *(const i32x4*)(gA + (off_) + 3072);          \
}

// one g: 8 MFMAs (2 independent chains seeded from zvec), quantize 32 elems
#define GCOMP(g_, p_) {                                                       \
  i32x4 b00 = *(const i32x4*)(rB + (g_) * 8192);                              \
  i32x4 b10 = *(const i32x4*)(rB + (g_) * 8192 + 512);                        \
  i32x16 c0 = __builtin_amdgcn_mfma_i32_32x32x32_i8(av[p_][0], b00, zvec, 0, 0, 0); \
  i32x16 c1 = __builtin_amdgcn_mfma_i32_32x32x32_i8(av[p_][0], b10, zvec, 0, 0, 0); \
  _Pragma("unroll")                                                           \
  for (int j = 1; j < 4; ++j) {                                               \
    i32x4 b0 = *(const i32x4*)(rB + (g_) * 8192 + j * 2048);                  \
    i32x4 b1 = *(const i32x4*)(rB + (g_) * 8192 + j * 2048 + 512);            \
    c0 = __builtin_amdgcn_mfma_i32_32x32x32_i8(av[p_][j], b0, c0, 0, 0, 0);   \
    c1 = __builtin_amdgcn_mfma_i32_32x32x32_i8(av[p_][j], b1, c1, 0, 0, 0);   \
  }                                                                           \
  _Pragma("unroll")                                                           \
  for (int e = 0; e < 16; ++e) {                                              \
    unsigned q0q = (__umul24((unsigned)c0[e], 51610u) + 524288u) >> 20;       \
    acc[0][e >> 2] += (int)(q0q << shr[e & 3]);                               \
    unsigned q1q = (__umul24((unsigned)c1[e], 51610u) + 524288u) >> 20;       \
    acc[1][e >> 2] += (int)(q1q << shr[e & 3]);                               \
  }                                                                           \
}

// unit u = i*4+g; prefetches unit u+1 (compile-time offsets), computes unit u
#define GUNIT(i_, g_, pref_) {                                                \
  const int p_ = ((i_) * 4 + (g_)) & 1;                                       \
  if (pref_) {                                                                \
    const int nu = (i_) * 4 + (g_) + 1;                                       \
    APREF((nu >> 2) * 65536 + (nu & 3) * 4096, 1 - p_)                        \
  }                                                                           \
  GCOMP(g_, p_)                                                               \
}

#define MBLK_EPI(i_) {                                                        \
  int sums[2][4];                                                             \
  _Pragma("unroll")                                                           \
  for (int cs = 0; cs < 2; ++cs)                                              \
    _Pragma("unroll")                                                         \
    for (int cc = 0; cc < 4; ++cc) {                                          \
      int v = acc[cs][cc];                                                    \
      v += __shfl_xor(v, 1, 64);                                              \
      v += __shfl_xor(v, 2, 64);                                              \
      v += __shfl_xor(v, 32, 64);                                             \
      sums[cs][cc] = v;                                                       \
      acc[cs][cc] = 0;                                                        \
    }                                                                         \
  if ((lane & 3) == 0 && lane < 32) {                                         \
    const int ol = lane >> 2;                                                 \
    _Pragma("unroll")                                                         \
    for (int cc = 0; cc < 4; ++cc) {                                          \
      int n = (mslice * 4 + (i_)) * 16 + wm * 4 + cc;                         \
      int d = dp[n * 2] + dp[n * 2 + 1];                                      \
      int b = n / 196, hw = n - b * 196;                                      \
      _Pragma("unroll")                                                       \
      for (int cs = 0; cs < 2; ++cs) {                                        \
        int o = cblk * 16 + cs * 8 + ol;                                      \
        size_t idx = ((size_t)(b * 1024 + o)) * 196 + hw;                     \
        out[idx] = (float)(sums[cs][cc] - d) * scale + y[idx];                \
      }                                                                       \
    }                                                                         \
  }                                                                           \
}

#define MBLK(i_, last_) {                                                     \
  GUNIT(i_, 0, 1) GUNIT(i_, 1, 1) GUNIT(i_, 2, 1) GUNIT(i_, 3, !(last_))     \
  MBLK_EPI(i_)                                                                \
}

__global__ __launch_bounds__(256, 4) void shortcutq_main_kernel(
    const char* __restrict__ act, const char* __restrict__ wgt,
    const int* __restrict__ dp, const float* __restrict__ y,
    const float* __restrict__ fin, float* __restrict__ out) {
  __shared__ __align__(16) char lds[32768];
  const int tid = threadIdx.x;
  const int cblk = blockIdx.x;    // 64: 16 o x 4 k cols
  const int mslice = blockIdx.y;  // 49: 4 mblks (16 tiles) each
  const int lane = tid & 63, wm = tid >> 6;

  // A: tile (mslice*16 + i*4 + wm); per-load 64 lanes x 16B contiguous
  const char* gA = act + (size_t)(mslice * 16 + wm) * 16384 + lane * 16;
  // B: coalesced DMA of the pre-swizzled 32 KB LDS image
  const char* gB = wgt + (size_t)cblk * 32768 + tid * 16;
  const char* rB = lds + (lane >> 5) * 1024 + (lane & 31) * 16;

  const int shb = 4 * (lane >> 5) + 2 * (lane & 3);
  int shr[4] = {shb, shb + 1, shb + 2, shb + 3};

  i32x4 av[2][4];
  int acc[2][4];
#pragma unroll
  for (int cs = 0; cs < 2; ++cs)
#pragma unroll
    for (int cc = 0; cc < 4; ++cc) acc[cs][cc] = 0;
  i32x16 zvec;
#pragma unroll
  for (int e = 0; e < 16; ++e) zvec[e] = 0;

  APREF(0, 0)                      // unit 0 A-frags, in flight with B DMA
#pragma unroll
  for (int l = 0; l < 8; ++l)
    gload(gB + l * 4096, lds + l * 4096 + tid * 16);
  __syncthreads();                 // the ONLY barrier

  const float scale = (float)((128.0 * (3.0 + 1.0 / 3.0)) / 63.0) *
                      (fin[1] / 127.0f) * (fin[0] / 255.0f);

  MBLK(0, 0) MBLK(1, 0) MBLK(2, 0) MBLK(3, 1)
}

extern "C" void kernel_launch(void* const* d_in, const int* in_sizes, int n_in,
                              void* d_out, int out_size, void* d_ws, size_t ws_size,
                              hipStream_t stream) {
  const float* x     = (const float*)d_in[0];
  const float* y     = (const float*)d_in[1];
  const float* gamma = (const float*)d_in[2];
  const float* beta  = (const float*)d_in[3];
  const float* mean  = (const float*)d_in[4];
  const float* var   = (const float*)d_in[5];
  const float* w     = (const float*)d_in[6];
  float* out = (float*)d_out;

  char* wsb = (char*)d_ws;
  float* fin    = (float*)(wsb + FIN_OFF);
  float* amaxp  = (float*)(wsb + AMAXP_OFF);
  float* wmaxp  = (float*)(wsb + WMAXP_OFF);
  float* chs    = (float*)(wsb + CHS_OFF);
  int*   dum    = (int*)(wsb + DUM_OFF);
  char*  actb   = wsb + ACT_OFF;
  char*  wgtb   = wsb + WGT_OFF;

  hipLaunchKernelGGL(prep1_kernel, dim3(1154), dim3(256), 0, stream,
                     x, w, gamma, beta, mean, var, amaxp, wmaxp, chs);
  hipLaunchKernelGGL(pack_xw_kernel, dim3(736), dim3(256), 0, stream,
                     x, mean, beta, chs, amaxp, w, wmaxp,
                     (unsigned*)actb, (unsigned*)wgtb, dum, fin);
  hipLaunchKernelGGL(shortcutq_main_kernel, dim3(64, 49), dim3(256), 0, stream,
                     actb, wgtb, dum, y, fin, out);
}